// Round 16
// baseline (668.522 us; speedup 1.0000x reference)
//
#include <hip/hip_runtime.h>

// LimbOrientationPredictor fused kernel (MI355X / gfx950) — round 16
// Base = round 15 (292us champion, VGPR 56, no spill).
// Round-16 change: expandB (68 VALU + 16 b128 scal reads per thread/tile) replaced
// by an MFMA: lf[:,0:128] = relu(X @ Wsm^T). Per-row LN scales fold into INPUTS
// (X = [f0*rs2, f1*rs2, L*rs2, rs2, cx*rsc.., rsc, view6, 1] bf16), gamma/beta into
// static weights Wsm (built in prep0, frag-ordered). lf columns reordered
// [l2|co|vf|pf|cf] so the expand output is contiguous; prep remaps W1's K dim.
// cur now global->reg (scal4 LDS deleted; X tile takes its slot, upper K zeroed once).

#define NTHR   1024
#define NBLK   256
#define NTILES 14336   // 917504 / 64
#define NROWS  917504
#define C2D    6.66662222251852f   // 1/(0.15+1e-6)
#define RAD    0.017453292519943295f
#define WS_WSM_OFF  98304          // 8KB wsm frags (bf16)
#define WS_STAT_OFF 106496         // 112B stats
#define WS_X_OFF    131072         // NROWS*32 B  (16 bf16 per row)
#define WS_CUR_OFF  (131072 + 29360128)   // NROWS*16 B (f32x4 cur per row)

typedef __bf16 bf16x8 __attribute__((ext_vector_type(8)));
typedef __bf16 bf16x4 __attribute__((ext_vector_type(4)));
typedef float  f32x4  __attribute__((ext_vector_type(4)));

// PARENT-5 / CHILD-5 packed as 4-bit nibbles, l = 0..13
#define PARENT_PK 0x10106097863120ull
#define CHILD_PK  0x677671b9a85342ull

// New lf column order: [l2 0-63 | co 64-95 | vf 96-127 | pf 128-191 | cf 192-255]
// W1 K-dim remap: k<96 -> k ; 96<=k<128 -> k+128 (old vf 224) ; k>=128 -> k-32 (old pf/cf 96/160)
__global__ __launch_bounds__(256) void prep_kernel(
    const float* __restrict__ w1, const float* __restrict__ w2,
    __bf16* __restrict__ wsb)
{
  const int u = blockIdx.x * 256 + threadIdx.x;   // 24*256 = 6144 tasks
  if (u < 4096) {
    const int lane = u & 63, t = u >> 6;
    const int f = t & 1, kk = (t >> 1) & 7, wn = t >> 4;
    const int col = wn * 32 + f * 16 + (lane & 15);
    const int kb  = kk * 32 + (lane >> 4) * 8;
    __bf16* dst = wsb + (size_t)u * 8;
    #pragma unroll
    for (int j = 0; j < 8; ++j) {
      const int kn = kb + j;
      const int ko = kn < 96 ? kn : (kn < 128 ? kn + 128 : kn - 32);
      dst[j] = (__bf16)w1[col * 256 + ko];
    }
  } else if (u < 6144) {
    const int v = u - 4096;
    const int lane = v & 63, t = v >> 6;
    const int f = t & 1, kk = (t >> 1) & 3, wn = t >> 3;
    const int col = wn * 32 + f * 16 + (lane & 15);
    const int kb  = kk * 32 + (lane >> 4) * 8;
    __bf16* dst = wsb + 32768 + (size_t)v * 8;
    #pragma unroll
    for (int j = 0; j < 8; ++j) dst[j] = (__bf16)w2[col * 128 + kb + j];
  }
}

// prep0 (128 threads): LN stats -> statg; Wsm (128 cols x 32 k, frag order) -> wsmg.
__global__ __launch_bounds__(128) void prep0_kernel(
    const float* __restrict__ cow, const float* __restrict__ cob,
    const float* __restrict__ cog, const float* __restrict__ cobe,
    const float* __restrict__ l2w, const float* __restrict__ l2b,
    const float* __restrict__ l2g, const float* __restrict__ l2be,
    const float* __restrict__ vw,  const float* __restrict__ vb,
    float* __restrict__ statg, __bf16* __restrict__ wsmg)
{
  const int tid = threadIdx.x;
  const int o64 = tid & 63;   // stats computed redundantly per wave
  const float w0 = l2w[o64 * 4 + 0], w1v = l2w[o64 * 4 + 1];
  const float w2v = l2w[o64 * 4 + 2] + C2D * l2w[o64 * 4 + 3];
  const float bo = l2b[o64];
  float v[14] = { w0, w1v, w2v, bo, w0 * w0, w0 * w1v, w0 * w2v,
                  w1v * w1v, w1v * w2v, w2v * w2v, w0 * bo, w1v * bo, w2v * bo, bo * bo };
  float c0 = 0.f, c1 = 0.f, c2 = 0.f, cb = 0.f;
  if (o64 < 32) { c0 = cow[o64 * 3 + 0]; c1 = cow[o64 * 3 + 1]; c2 = cow[o64 * 3 + 2]; cb = cob[o64]; }
  float u[14] = { c0, c1, c2, cb, c0 * c0, c0 * c1, c0 * c2,
                  c1 * c1, c1 * c2, c2 * c2, c0 * cb, c1 * cb, c2 * cb, cb * cb };
  #pragma unroll
  for (int k = 0; k < 14; ++k) {
    #pragma unroll
    for (int m = 1; m < 64; m <<= 1) { v[k] += __shfl_xor(v[k], m, 64); u[k] += __shfl_xor(u[k], m, 64); }
  }
  const float i64 = 1.f / 64.f, i32 = 1.f / 32.f;
  const float lmx = v[0] * i64, lmy = v[1] * i64, lmz = v[2] * i64, lmb = v[3] * i64;
  const float cmx = u[0] * i32, cmy = u[1] * i32, cmz = u[2] * i32, cmb = u[3] * i32;
  if (tid == 0) {
    statg[0] = lmx; statg[1] = lmy; statg[2] = lmz; statg[3] = lmb;
    statg[4] = v[4] * i64 - lmx * lmx;        statg[5] = 2.f * (v[5] * i64 - lmx * lmy);
    statg[6] = 2.f * (v[6] * i64 - lmx * lmz); statg[7] = v[7] * i64 - lmy * lmy;
    statg[8] = 2.f * (v[8] * i64 - lmy * lmz); statg[9] = v[9] * i64 - lmz * lmz;
    statg[10] = 2.f * (v[10] * i64 - lmx * lmb); statg[11] = 2.f * (v[11] * i64 - lmy * lmb);
    statg[12] = 2.f * (v[12] * i64 - lmz * lmb); statg[13] = v[13] * i64 - lmb * lmb;
    statg[14] = cmx; statg[15] = cmy; statg[16] = cmz; statg[17] = cmb;
    statg[18] = u[4] * i32 - cmx * cmx;        statg[19] = 2.f * (u[5] * i32 - cmx * cmy);
    statg[20] = 2.f * (u[6] * i32 - cmx * cmz); statg[21] = u[7] * i32 - cmy * cmy;
    statg[22] = 2.f * (u[8] * i32 - cmy * cmz); statg[23] = u[9] * i32 - cmz * cmz;
    statg[24] = 2.f * (u[10] * i32 - cmx * cmb); statg[25] = 2.f * (u[11] * i32 - cmy * cmb);
    statg[26] = 2.f * (u[12] * i32 - cmz * cmb); statg[27] = u[13] * i32 - cmb * cmb;
  }
  // ---- build Wsm column tid (0..127) ----
  float W[16];
  #pragma unroll
  for (int k = 0; k < 16; ++k) W[k] = 0.f;
  const int col = tid;
  if (col < 64) {            // l2: y = relu(g*(lwc.x)*rs2 + g*lbc*rs2 + be)
    const float g = l2g[col], be = l2be[col];
    W[0] = g * (l2w[col * 4 + 0] - lmx);
    W[1] = g * (l2w[col * 4 + 1] - lmy);
    W[2] = g * ((l2w[col * 4 + 2] + C2D * l2w[col * 4 + 3]) - lmz);
    W[3] = g * (l2b[col] - lmb);
    W[14] = be;
  } else if (col < 96) {     // co
    const int o = col - 64;
    const float g = cog[o], be = cobe[o];
    W[4] = g * (cow[o * 3 + 0] - cmx);
    W[5] = g * (cow[o * 3 + 1] - cmy);
    W[6] = g * (cow[o * 3 + 2] - cmz);
    W[7] = g * (cob[o] - cmb);
    W[14] = be;
  } else {                   // vf
    const int o = col - 96;
    W[8]  = vw[o * 7 + 0];
    W[9]  = vw[o * 7 + 1] + vw[o * 7 + 5];
    W[10] = vw[o * 7 + 2];
    W[11] = vw[o * 7 + 3];
    W[12] = vw[o * 7 + 4];
    W[13] = vw[o * 7 + 6];
    W[14] = vb[o];
  }
  const int mp = col >> 5, f = (col >> 4) & 1, lcol = col & 15;
  #pragma unroll
  for (int kq = 0; kq < 4; ++kq) {
    #pragma unroll
    for (int j = 0; j < 8; ++j) {
      const int k = kq * 8 + j;
      wsmg[(size_t)(((mp * 2 + f) * 64 + kq * 16 + lcol)) * 8 + j] =
          (__bf16)(k < 16 ? W[k] : 0.f);
    }
  }
}

// prep2: per-row X (16 bf16) + cur (f32x4).
__global__ __launch_bounds__(256) void prep2_kernel(
    const float* __restrict__ p3g, const float* __restrict__ az,
    const float* __restrict__ el,  const float* __restrict__ p2d,
    const float* __restrict__ statg, __bf16* __restrict__ Xg,
    f32x4* __restrict__ curg)
{
  const int r = blockIdx.x * 256 + threadIdx.x;   // 3584*256 = 917504 exact
  const unsigned rg = (unsigned)r;
  const unsigned b = rg / 14u;
  const int l = (int)(rg - b * 14u);
  const int p = 5 + (int)((PARENT_PK >> (4 * l)) & 15ull);
  const int c = 5 + (int)((CHILD_PK  >> (4 * l)) & 15ull);
  const float* p3 = p3g + (size_t)b * 51;
  const float dx = p3[c * 3 + 0] - p3[p * 3 + 0];
  const float dy = p3[c * 3 + 1] - p3[p * 3 + 1];
  const float dz = p3[c * 3 + 2] - p3[p * 3 + 2];
  const float* q2 = p2d + (size_t)b * 34;
  const float vx = q2[c * 2 + 0] - q2[p * 2 + 0];
  const float vy = q2[c * 2 + 1] - q2[p * 2 + 1];
  const float sazv = az[b], selv = el[b];

  const float ci = 1.f / fmaxf(sqrtf(dx * dx + dy * dy + dz * dz), 1e-6f);
  const float cx = dx * ci, cy = dy * ci, cz = dz * ci;
  const float L  = sqrtf(vx * vx + vy * vy);
  const float il = 1.f / (L + 1e-6f);
  const float f0 = vx * il, f1 = vy * il;
  const float azr = sazv * RAD, elr = selv * RAD;
  const float sa = __sinf(azr), ca = __cosf(azr);
  const float se = __sinf(elr), ce = __cosf(elr);
  const float vl = statg[4] * f0 * f0 + statg[7] * f1 * f1 + statg[9] * L * L +
                   statg[5] * f0 * f1 + statg[6] * f0 * L + statg[8] * f1 * L +
                   statg[10] * f0 + statg[11] * f1 + statg[12] * L + statg[13];
  const float vc = statg[18] * cx * cx + statg[21] * cy * cy + statg[23] * cz * cz +
                   statg[19] * cx * cy + statg[20] * cx * cz + statg[22] * cy * cz +
                   statg[24] * cx + statg[25] * cy + statg[26] * cz + statg[27];
  const float rs2 = rsqrtf(vl + 1e-5f);
  const float rsc = rsqrtf(vc + 1e-5f);

  __bf16 xr[16];
  xr[0] = (__bf16)(f0 * rs2);  xr[1] = (__bf16)(f1 * rs2);
  xr[2] = (__bf16)(L * rs2);   xr[3] = (__bf16)rs2;
  xr[4] = (__bf16)(cx * rsc);  xr[5] = (__bf16)(cy * rsc);
  xr[6] = (__bf16)(cz * rsc);  xr[7] = (__bf16)rsc;
  xr[8] = (__bf16)(sa * ce);   xr[9] = (__bf16)se;
  xr[10] = (__bf16)(ca * ce);  xr[11] = (__bf16)sa;
  xr[12] = (__bf16)ca;         xr[13] = (__bf16)ce;
  xr[14] = (__bf16)1.0f;       xr[15] = (__bf16)0.0f;
  uint4* xd = (uint4*)(Xg + (size_t)r * 16);
  xd[0] = *(const uint4*)&xr[0];
  xd[1] = *(const uint4*)&xr[8];
  f32x4 cu; cu[0] = cx; cu[1] = cy; cu[2] = cz; cu[3] = 0.f;
  curg[r] = cu;
}

struct Smem {
  __bf16 w1f[32768];     // 65536B
  __bf16 w2f[16384];     // 32768B
  __bf16 lf[64][264];    // 33792B feature tile [l2|co|vf|pf|cf]
  __bf16 h [64][132];    // 16896B post-LN h tile
  __bf16 X [64][40];     // 5120B expand inputs (k 0-15 staged; 16-39 zeroed once)
                         //   fallback: reinterpreted as f32x4 scal4[256] (4096B)
  float  w3c[384];       // 1536B
  float  h1b[128], hg[128], hbe[128], h2b[128];  // 2048B
  float  partG1[512];    // 2048B
  float  partG2[768];    // 3072B
};                        // total 162816B <= 163840 -> 1 block/CU, 16 waves

__device__ __forceinline__ float RFL(float x) {
  return __uint_as_float((unsigned)__builtin_amdgcn_readfirstlane((int)__float_as_uint(x)));
}

template<bool PRECOMP>
__global__ __launch_bounds__(NTHR, 4) void limb_kernel(
    const float* __restrict__ jf,  const float* __restrict__ p3g,
    const float* __restrict__ az,  const float* __restrict__ el,
    const float* __restrict__ p2d,
    const float* __restrict__ cow, const float* __restrict__ cob,
    const float* __restrict__ cog, const float* __restrict__ cobe,
    const float* __restrict__ l2w, const float* __restrict__ l2b,
    const float* __restrict__ l2g, const float* __restrict__ l2be,
    const float* __restrict__ vw,  const float* __restrict__ vb,
    const float* __restrict__ h1bg, const float* __restrict__ hgg,
    const float* __restrict__ hbeg, const float* __restrict__ h2bg,
    const float* __restrict__ w3,  const float* __restrict__ h3bg,
    const __bf16* __restrict__ wsb, const __bf16* __restrict__ Xg,
    const f32x4* __restrict__ curg,
    float* __restrict__ out)
{
  __shared__ Smem sm;
  const int tid  = threadIdx.x;
  const int wave = tid >> 6;
  const int lane = tid & 63;
  const int lrow = lane & 15, lk8 = lane >> 4;
  const int mp = wave >> 2, nt = wave & 3;
  const int nrow = nt * 16 + lrow;
  const int cb0 = mp * 32 + lk8 * 4;
  const int cb1 = cb0 + 16;
  const int myrow0 = wave * 4;

  const bf16x8* __restrict__ wsm8 = (const bf16x8*)(wsb + 49152);  // 98304B offset

  // ---- one-time staging ----
  {
    const uint4* s1 = (const uint4*)wsb;
    uint4* d1 = (uint4*)sm.w1f;
    for (int i = tid; i < 4096; i += NTHR) d1[i] = s1[i];
    const uint4* s2 = (const uint4*)(wsb + 32768);
    uint4* d2 = (uint4*)sm.w2f;
    for (int i = tid; i < 2048; i += NTHR) d2[i] = s2[i];
  }
  for (int i = tid; i < 64 * 40; i += NTHR) ((__bf16*)sm.X)[i] = (__bf16)0.0f;
  if (tid < 384) sm.w3c[tid] = w3[tid];
  if (tid < 128) {
    sm.h1b[tid] = h1bg[tid]; sm.hg[tid] = hgg[tid];
    sm.hbe[tid] = hbeg[tid]; sm.h2b[tid] = h2bg[tid];
  }
  const float h3b0 = h3bg[0], h3b1 = h3bg[1], h3b2 = h3bg[2];

  // ---- closed-form LN stats (fallback path only uses Q terms; means for both) ----
  float lQxx, lQxy2, lQxz2, lQyy, lQyz2, lQzz, lrx2, lry2, lrz2, ls0;
  float lmx, lmy, lmz, lmb;
  {
    float s1x = 0, s1y = 0, s1z = 0, sb = 0;
    float sxx = 0, sxy = 0, sxz = 0, syy = 0, syz = 0, szz = 0;
    float sbx = 0, sby = 0, sbz = 0, sbb = 0;
    for (int o = 0; o < 64; ++o) {
      const float w0 = l2w[o * 4 + 0], w1v = l2w[o * 4 + 1];
      const float w2v = l2w[o * 4 + 2] + C2D * l2w[o * 4 + 3];
      const float bo = l2b[o];
      s1x += w0; s1y += w1v; s1z += w2v; sb += bo;
      sxx += w0 * w0; sxy += w0 * w1v; sxz += w0 * w2v;
      syy += w1v * w1v; syz += w1v * w2v; szz += w2v * w2v;
      sbx += w0 * bo; sby += w1v * bo; sbz += w2v * bo; sbb += bo * bo;
    }
    const float i = 1.f / 64.f;
    lmx = RFL(s1x * i); lmy = RFL(s1y * i); lmz = RFL(s1z * i); lmb = RFL(sb * i);
    lQxx = RFL(sxx * i - lmx * lmx); lQxy2 = RFL(2.f * (sxy * i - lmx * lmy));
    lQxz2 = RFL(2.f * (sxz * i - lmx * lmz)); lQyy = RFL(syy * i - lmy * lmy);
    lQyz2 = RFL(2.f * (syz * i - lmy * lmz)); lQzz = RFL(szz * i - lmz * lmz);
    lrx2 = RFL(2.f * (sbx * i - lmx * lmb)); lry2 = RFL(2.f * (sby * i - lmy * lmb));
    lrz2 = RFL(2.f * (sbz * i - lmz * lmb)); ls0 = RFL(sbb * i - lmb * lmb);
  }
  float cQxx, cQxy2, cQxz2, cQyy, cQyz2, cQzz, crx2, cry2, crz2, cs0;
  float cmx, cmy, cmz, cmb;
  {
    float s1x = 0, s1y = 0, s1z = 0, sb = 0;
    float sxx = 0, sxy = 0, sxz = 0, syy = 0, syz = 0, szz = 0;
    float sbx = 0, sby = 0, sbz = 0, sbb = 0;
    for (int o = 0; o < 32; ++o) {
      const float w0 = cow[o * 3 + 0], w1v = cow[o * 3 + 1], w2v = cow[o * 3 + 2];
      const float bo = cob[o];
      s1x += w0; s1y += w1v; s1z += w2v; sb += bo;
      sxx += w0 * w0; sxy += w0 * w1v; sxz += w0 * w2v;
      syy += w1v * w1v; syz += w1v * w2v; szz += w2v * w2v;
      sbx += w0 * bo; sby += w1v * bo; sbz += w2v * bo; sbb += bo * bo;
    }
    const float i = 1.f / 32.f;
    cmx = RFL(s1x * i); cmy = RFL(s1y * i); cmz = RFL(s1z * i); cmb = RFL(sb * i);
    cQxx = RFL(sxx * i - cmx * cmx); cQxy2 = RFL(2.f * (sxy * i - cmx * cmy));
    cQxz2 = RFL(2.f * (sxz * i - cmx * cmz)); cQyy = RFL(syy * i - cmy * cmy);
    cQyz2 = RFL(2.f * (syz * i - cmy * cmz)); cQzz = RFL(szz * i - cmz * cmz);
    crx2 = RFL(2.f * (sbx * i - cmx * cmb)); cry2 = RFL(2.f * (sby * i - cmy * cmb));
    crz2 = RFL(2.f * (sbz * i - cmz * cmb)); cs0 = RFL(sbb * i - cmb * cmb);
  }

  // ---- per-lane small-net params (fallback expandB only) ----
  const float lwc0 = l2w[lane * 4 + 0] - lmx;
  const float lwc1 = l2w[lane * 4 + 1] - lmy;
  const float lwc2 = (l2w[lane * 4 + 2] + C2D * l2w[lane * 4 + 3]) - lmz;
  const float lbc  = l2b[lane] - lmb;
  const float lgv  = l2g[lane], lbev = l2be[lane];
  float u0, u1, u2, u3, u4, u5, u6;
  if (lane < 32) {
    u0 = cow[lane * 3 + 0] - cmx; u1 = cow[lane * 3 + 1] - cmy;
    u2 = cow[lane * 3 + 2] - cmz; u3 = cob[lane] - cmb;
    u4 = cog[lane]; u5 = cobe[lane]; u6 = 0.f;
  } else {
    const int o = lane - 32;
    u0 = vw[o * 7 + 0]; u1 = vw[o * 7 + 1] + vw[o * 7 + 5];
    u2 = vw[o * 7 + 2]; u3 = vw[o * 7 + 3];
    u4 = vw[o * 7 + 4]; u5 = vw[o * 7 + 6]; u6 = vb[o];
  }

  f32x4* const scal4u = (f32x4*)&sm.X[0][0];   // fallback union

  // ---- helpers ----
  auto jf_src = [&](int rg0x, int round) -> const float* {
    const int task = wave * 8 + round * 4 + lk8;
    const int row = task >> 1, half = task & 1;
    const unsigned rg = (unsigned)(rg0x + row);
    const unsigned b = rg / 14u;
    const int l = (int)(rg - b * 14u);
    const int j = half ? 5 + (int)((CHILD_PK >> (4 * l)) & 15ull)
                       : 5 + (int)((PARENT_PK >> (4 * l)) & 15ull);
    return jf + ((size_t)b * 17 + (size_t)j) * 64 + lrow * 4;
  };
  auto jf_store = [&](int round, float4 v) {
    const int task = wave * 8 + round * 4 + lk8;
    const int row = task >> 1, half = task & 1;
    bf16x4 o; o[0] = (__bf16)v.x; o[1] = (__bf16)v.y; o[2] = (__bf16)v.z; o[3] = (__bf16)v.w;
    *(bf16x4*)&sm.lf[row][(half ? 192 : 128) + lrow * 4] = o;   // pf@128, cf@192
  };
  struct G12 { float p3p0, p3p1, p3p2, p3c0, p3c1, p3c2, q2p0, q2p1, q2c0, q2c1, sazv, selv; };
  auto gather12_row = [&](int rgl) -> G12 {
    G12 g;
    const unsigned rg = (unsigned)rgl;
    const unsigned b = rg / 14u;
    const int l = (int)(rg - b * 14u);
    const int p = 5 + (int)((PARENT_PK >> (4 * l)) & 15ull);
    const int c = 5 + (int)((CHILD_PK  >> (4 * l)) & 15ull);
    const float* p3 = p3g + (size_t)b * 51;
    g.p3p0 = p3[p * 3 + 0]; g.p3p1 = p3[p * 3 + 1]; g.p3p2 = p3[p * 3 + 2];
    g.p3c0 = p3[c * 3 + 0]; g.p3c1 = p3[c * 3 + 1]; g.p3c2 = p3[c * 3 + 2];
    const float* q2 = p2d + (size_t)b * 34;
    g.q2p0 = q2[p * 2 + 0]; g.q2p1 = q2[p * 2 + 1];
    g.q2c0 = q2[c * 2 + 0]; g.q2c1 = q2[c * 2 + 1];
    g.sazv = az[b]; g.selv = el[b];
    return g;
  };
  auto scal_write = [&](int row, const G12& g) {   // fallback only
    const float dx = g.p3c0 - g.p3p0, dy = g.p3c1 - g.p3p1, dz = g.p3c2 - g.p3p2;
    const float ci = 1.f / fmaxf(sqrtf(dx * dx + dy * dy + dz * dz), 1e-6f);
    const float cx = dx * ci, cy = dy * ci, cz = dz * ci;
    const float vx = g.q2c0 - g.q2p0, vy = g.q2c1 - g.q2p1;
    const float L  = sqrtf(vx * vx + vy * vy);
    const float il = 1.f / (L + 1e-6f);
    const float f0 = vx * il, f1 = vy * il;
    const float azr = g.sazv * RAD, elr = g.selv * RAD;
    const float sa = __sinf(azr), ca = __cosf(azr);
    const float se = __sinf(elr), ce = __cosf(elr);
    const float vl = lQxx * f0 * f0 + lQyy * f1 * f1 + lQzz * L * L +
                     lQxy2 * f0 * f1 + lQxz2 * f0 * L + lQyz2 * f1 * L +
                     lrx2 * f0 + lry2 * f1 + lrz2 * L + ls0;
    const float vc = cQxx * cx * cx + cQyy * cy * cy + cQzz * cz * cz +
                     cQxy2 * cx * cy + cQxz2 * cx * cz + cQyz2 * cy * cz +
                     crx2 * cx + cry2 * cy + crz2 * cz + cs0;
    f32x4 s0; s0[0] = cx; s0[1] = cy; s0[2] = cz; s0[3] = f0;
    f32x4 s1; s1[0] = f1; s1[1] = L; s1[2] = rsqrtf(vl + 1e-5f); s1[3] = rsqrtf(vc + 1e-5f);
    f32x4 s2; s2[0] = sa * ce; s2[1] = se; s2[2] = ca * ce; s2[3] = sa;
    f32x4 s3; s3[0] = ca; s3[1] = ce; s3[2] = 0.f; s3[3] = 0.f;
    scal4u[row * 4 + 0] = s0; scal4u[row * 4 + 1] = s1;
    scal4u[row * 4 + 2] = s2; scal4u[row * 4 + 3] = s3;
  };
  auto expandB = [&]() {   // fallback only (new lf layout: vf at 96)
    #pragma unroll
    for (int rr = 0; rr < 4; ++rr) {
      const int row = myrow0 + rr;
      const f32x4 s0 = scal4u[row * 4 + 0];
      const f32x4 s1 = scal4u[row * 4 + 1];
      const f32x4 s2 = scal4u[row * 4 + 2];
      const f32x4 s3 = scal4u[row * 4 + 3];
      {
        const float a = lwc0 * s0[3] + lwc1 * s1[0] + lwc2 * s1[1] + lbc;
        sm.lf[row][lane] = (__bf16)fmaxf(a * s1[2] * lgv + lbev, 0.f);
      }
      if (lane < 32) {
        const float a = u0 * s0[0] + u1 * s0[1] + u2 * s0[2] + u3;
        sm.lf[row][64 + lane] = (__bf16)fmaxf(a * s1[3] * u4 + u5, 0.f);
      } else {
        const float a = u0 * s2[0] + u1 * s2[1] + u2 * s2[2] + u3 * s2[3] +
                        u4 * s3[0] + u5 * s3[1] + u6;
        sm.lf[row][96 + (lane - 32)] = (__bf16)fmaxf(a, 0.f);
      }
    }
  };
  auto expandMFMA = [&]() {   // PRECOMP: lf[:,0:128] = relu(X @ Wsm^T)
    const bf16x8 fbX = *(const bf16x8*)&sm.X[nrow][lk8 * 8];
    const bf16x8 wa0 = wsm8[(mp * 2 + 0) * 64 + lane];
    const bf16x8 wa1 = wsm8[(mp * 2 + 1) * 64 + lane];
    f32x4 e0 = {0.f, 0.f, 0.f, 0.f}, e1 = e0;
    e0 = __builtin_amdgcn_mfma_f32_16x16x32_bf16(wa0, fbX, e0, 0, 0, 0);
    e1 = __builtin_amdgcn_mfma_f32_16x16x32_bf16(wa1, fbX, e1, 0, 0, 0);
    bf16x4 y0, y1;
    #pragma unroll
    for (int j = 0; j < 4; ++j) {
      y0[j] = (__bf16)fmaxf(e0[j], 0.f);
      y1[j] = (__bf16)fmaxf(e1[j], 0.f);
    }
    *(bf16x4*)&sm.lf[nrow][cb0] = y0;
    *(bf16x4*)&sm.lf[nrow][cb1] = y1;
  };

  // ---- prologue: stage tile0 fully ----
  {
    const int rg0 = blockIdx.x * 64;
    jf_store(0, *(const float4*)jf_src(rg0, 0));
    jf_store(1, *(const float4*)jf_src(rg0, 1));
    if (PRECOMP) {
      if (lane < 8) {   // X(t0): row = myrow0+(lane>>1), chunk = lane&1 (16B)
        const int row = myrow0 + (lane >> 1), ch = lane & 1;
        *(uint4*)&sm.X[row][ch * 8] =
            ((const uint4*)(Xg + (size_t)(rg0 + row) * 16))[ch];
      }
    } else if (lane < 4) {
      scal_write(myrow0 + lane, gather12_row(rg0 + myrow0 + lane));
    }
    __syncthreads();   // X/scal visible (also covers zero-fill + weights)
    if (PRECOMP) expandMFMA(); else expandB();
  }
  __syncthreads();

  float curx = 0.f, cury = 0.f, curz = 0.f;
  int prevT = -1;

  for (int tile = blockIdx.x; tile < NTILES; tile += NBLK) {
    const int ntile = tile + NBLK;
    const bool pv = ntile < NTILES;

    // ===== G1 phase: prefetch issue + finalize(t-1) + G1 MFMA =====
    float4 jva = {0.f, 0.f, 0.f, 0.f}, jvb = jva;
    uint4 xv = {0, 0, 0, 0};
    f32x4 cn = {0.f, 0.f, 0.f, 0.f};
    G12 g = {};
    if (PRECOMP && lane < 4) cn = curg[(size_t)tile * 64 + myrow0 + lane];  // cur(t)
    if (pv) {
      jva = *(const float4*)jf_src(ntile * 64, 0);
      jvb = *(const float4*)jf_src(ntile * 64, 1);
      if (PRECOMP) {
        if (lane < 8) {
          const int row = myrow0 + (lane >> 1), ch = lane & 1;
          xv = ((const uint4*)(Xg + (size_t)(ntile * 64 + row) * 16))[ch];
        }
      } else if (lane < 4) {
        g = gather12_row(ntile * 64 + myrow0 + lane);
      }
    }
    if (prevT >= 0 && lane < 4) {   // finalize(prevT)
      const int r = myrow0 + lane;
      const f32x4 q0 = *(const f32x4*)&sm.partG2[r * 12];
      const f32x4 q1 = *(const f32x4*)&sm.partG2[r * 12 + 4];
      const f32x4 q2 = *(const f32x4*)&sm.partG2[r * 12 + 8];
      const float ox = curx + q0[0] + q0[1] + q0[2] + q0[3] + h3b0;
      const float oy = cury + q1[0] + q1[1] + q1[2] + q1[3] + h3b1;
      const float oz = curz + q2[0] + q2[1] + q2[2] + q2[3] + h3b2;
      const float nn = sqrtf(ox * ox + oy * oy + oz * oz);
      const float iv = 1.f / fmaxf(nn, 1e-6f);
      const size_t o0 = (size_t)(prevT * 64 + r) * 3;
      out[o0 + 0] = ox * iv; out[o0 + 1] = oy * iv; out[o0 + 2] = oz * iv;
    }
    f32x4 a0 = {0.f, 0.f, 0.f, 0.f}, a1 = a0;
    #pragma unroll
    for (int kk = 0; kk < 8; ++kk) {
      const bf16x8 fb  = *(const bf16x8*)&sm.lf[nrow][kk * 32 + lk8 * 8];
      const bf16x8 fa0 = *(const bf16x8*)&sm.w1f[(((mp * 8 + kk) * 2 + 0) * 64 + lane) * 8];
      const bf16x8 fa1 = *(const bf16x8*)&sm.w1f[(((mp * 8 + kk) * 2 + 1) * 64 + lane) * 8];
      a0 = __builtin_amdgcn_mfma_f32_16x16x32_bf16(fa0, fb, a0, 0, 0, 0);
      a1 = __builtin_amdgcn_mfma_f32_16x16x32_bf16(fa1, fb, a1, 0, 0, 0);
    }
    const f32x4 hb0 = *(const f32x4*)&sm.h1b[cb0];
    const f32x4 hb1 = *(const f32x4*)&sm.h1b[cb1];
    float v0[4], v1[4], ss = 0.f, qq = 0.f;
    #pragma unroll
    for (int j = 0; j < 4; ++j) {
      v0[j] = a0[j] + hb0[j]; v1[j] = a1[j] + hb1[j];
      ss += v0[j] + v1[j];
      qq = fmaf(v0[j], v0[j], qq); qq = fmaf(v1[j], v1[j], qq);
    }
    ss += __shfl_xor(ss, 16, 64); ss += __shfl_xor(ss, 32, 64);
    qq += __shfl_xor(qq, 16, 64); qq += __shfl_xor(qq, 32, 64);
    if (lk8 == 0) *(float2*)&sm.partG1[nrow * 8 + mp * 2] = make_float2(ss, qq);
    __syncthreads();   // B1

    // ===== LN phase: apply + write h ; stage X(t+1) to LDS =====
    {
      const f32x4 pa = *(const f32x4*)&sm.partG1[nrow * 8];
      const f32x4 pb = *(const f32x4*)&sm.partG1[nrow * 8 + 4];
      const float mean = (pa[0] + pa[2] + pb[0] + pb[2]) * (1.f / 128.f);
      const float var  = (pa[1] + pa[3] + pb[1] + pb[3]) * (1.f / 128.f) - mean * mean;
      const float rs = rsqrtf(var + 1e-5f);
      const f32x4 g0 = *(const f32x4*)&sm.hg[cb0],  g1 = *(const f32x4*)&sm.hg[cb1];
      const f32x4 e0 = *(const f32x4*)&sm.hbe[cb0], e1 = *(const f32x4*)&sm.hbe[cb1];
      bf16x4 y0, y1;
      #pragma unroll
      for (int j = 0; j < 4; ++j) {
        float t0 = (v0[j] - mean) * rs * g0[j] + e0[j]; t0 = (t0 > 0.f) ? t0 : 0.2f * t0;
        float t1 = (v1[j] - mean) * rs * g1[j] + e1[j]; t1 = (t1 > 0.f) ? t1 : 0.2f * t1;
        y0[j] = (__bf16)t0; y1[j] = (__bf16)t1;
      }
      *(bf16x4*)&sm.h[nrow][cb0] = y0;
      *(bf16x4*)&sm.h[nrow][cb1] = y1;
    }
    if (PRECOMP && pv && lane < 8) {   // X LDS last read ended at B3(t-1)
      const int row = myrow0 + (lane >> 1), ch = lane & 1;
      *(uint4*)&sm.X[row][ch * 8] = xv;
    }
    __syncthreads();   // B2

    // ===== G2 phase: G2 MFMA + epilogue + stage(t+1) + expand(t+1) =====
    f32x4 d0 = {0.f, 0.f, 0.f, 0.f}, d1 = d0;
    #pragma unroll
    for (int kk = 0; kk < 4; ++kk) {
      const bf16x8 fbh = *(const bf16x8*)&sm.h[nrow][kk * 32 + lk8 * 8];
      const bf16x8 fa0 = *(const bf16x8*)&sm.w2f[(((mp * 4 + kk) * 2 + 0) * 64 + lane) * 8];
      const bf16x8 fa1 = *(const bf16x8*)&sm.w2f[(((mp * 4 + kk) * 2 + 1) * 64 + lane) * 8];
      d0 = __builtin_amdgcn_mfma_f32_16x16x32_bf16(fa0, fbh, d0, 0, 0, 0);
      d1 = __builtin_amdgcn_mfma_f32_16x16x32_bf16(fa1, fbh, d1, 0, 0, 0);
    }
    if (pv) { jf_store(0, jva); jf_store(1, jvb); }   // lf free since B1
    if (lane < 4) {
      if (PRECOMP) {
        curx = cn[0]; cury = cn[1]; curz = cn[2];
      } else {
        const f32x4 cu = scal4u[(myrow0 + lane) * 4];
        curx = cu[0]; cury = cu[1]; curz = cu[2];
        if (pv) scal_write(myrow0 + lane, g);
      }
    }
    {
      const f32x4 b20 = *(const f32x4*)&sm.h2b[cb0], b21 = *(const f32x4*)&sm.h2b[cb1];
      const f32x4 wx0 = *(const f32x4*)&sm.w3c[cb0],        wx1 = *(const f32x4*)&sm.w3c[cb1];
      const f32x4 wy0 = *(const f32x4*)&sm.w3c[128 + cb0],  wy1 = *(const f32x4*)&sm.w3c[128 + cb1];
      const f32x4 wz0 = *(const f32x4*)&sm.w3c[256 + cb0],  wz1 = *(const f32x4*)&sm.w3c[256 + cb1];
      float p0 = 0.f, p1 = 0.f, p2 = 0.f;
      #pragma unroll
      for (int j = 0; j < 4; ++j) {
        float x0 = d0[j] + b20[j]; x0 = (x0 > 0.f) ? x0 : 0.2f * x0;
        float x1 = d1[j] + b21[j]; x1 = (x1 > 0.f) ? x1 : 0.2f * x1;
        p0 = fmaf(x0, wx0[j], fmaf(x1, wx1[j], p0));
        p1 = fmaf(x0, wy0[j], fmaf(x1, wy1[j], p1));
        p2 = fmaf(x0, wz0[j], fmaf(x1, wz1[j], p2));
      }
      p0 += __shfl_xor(p0, 16, 64); p0 += __shfl_xor(p0, 32, 64);
      p1 += __shfl_xor(p1, 16, 64); p1 += __shfl_xor(p1, 32, 64);
      p2 += __shfl_xor(p2, 16, 64); p2 += __shfl_xor(p2, 32, 64);
      if (lk8 == 0) {
        sm.partG2[nrow * 12 + 0 + mp] = p0;
        sm.partG2[nrow * 12 + 4 + mp] = p1;
        sm.partG2[nrow * 12 + 8 + mp] = p2;
      }
    }
    if (pv) { if (PRECOMP) expandMFMA(); else expandB(); }
    __syncthreads();     // B3
    prevT = tile;
  }

  // ---- epilogue: finalize the last tile ----
  if (lane < 4) {
    const int r = myrow0 + lane;
    const f32x4 q0 = *(const f32x4*)&sm.partG2[r * 12];
    const f32x4 q1 = *(const f32x4*)&sm.partG2[r * 12 + 4];
    const f32x4 q2 = *(const f32x4*)&sm.partG2[r * 12 + 8];
    const float ox = curx + q0[0] + q0[1] + q0[2] + q0[3] + h3b0;
    const float oy = cury + q1[0] + q1[1] + q1[2] + q1[3] + h3b1;
    const float oz = curz + q2[0] + q2[1] + q2[2] + q2[3] + h3b2;
    const float nn = sqrtf(ox * ox + oy * oy + oz * oz);
    const float iv = 1.f / fmaxf(nn, 1e-6f);
    const size_t o0 = (size_t)(prevT * 64 + r) * 3;
    out[o0 + 0] = ox * iv; out[o0 + 1] = oy * iv; out[o0 + 2] = oz * iv;
  }
}

extern "C" void kernel_launch(void* const* d_in, const int* in_sizes, int n_in,
                              void* d_out, int out_size, void* d_ws, size_t ws_size,
                              hipStream_t stream) {
  (void)in_sizes; (void)n_in; (void)out_size;
  const float* jf   = (const float*)d_in[0];
  // d_in[1] = pose_2d (unused by the reference)
  const float* p3   = (const float*)d_in[2];
  const float* az   = (const float*)d_in[3];
  const float* el   = (const float*)d_in[4];
  const float* p2d  = (const float*)d_in[5];
  const float* cow  = (const float*)d_in[6];
  const float* cob  = (const float*)d_in[7];
  const float* cog  = (const float*)d_in[8];
  const float* cobe = (const float*)d_in[9];
  const float* l2w  = (const float*)d_in[10];
  const float* l2b  = (const float*)d_in[11];
  const float* l2g  = (const float*)d_in[12];
  const float* l2be = (const float*)d_in[13];
  const float* vw   = (const float*)d_in[14];
  const float* vb   = (const float*)d_in[15];
  const float* w1   = (const float*)d_in[16];
  const float* h1b  = (const float*)d_in[17];
  const float* hg   = (const float*)d_in[18];
  const float* hbe  = (const float*)d_in[19];
  const float* w2   = (const float*)d_in[20];
  const float* h2b  = (const float*)d_in[21];
  const float* w3   = (const float*)d_in[22];
  const float* h3b  = (const float*)d_in[23];

  __bf16* wsb   = (__bf16*)d_ws;
  __bf16* wsmg  = (__bf16*)((char*)d_ws + WS_WSM_OFF);
  float*  statg = (float*)((char*)d_ws + WS_STAT_OFF);
  __bf16* Xg    = (__bf16*)((char*)d_ws + WS_X_OFF);
  f32x4*  curg  = (f32x4*)((char*)d_ws + WS_CUR_OFF);

  const size_t ws_need = (size_t)WS_CUR_OFF + (size_t)NROWS * 16;
  const bool pre = ws_size >= ws_need;

  prep_kernel<<<dim3(24), dim3(256), 0, stream>>>(w1, w2, wsb);
  if (pre) {
    prep0_kernel<<<dim3(1), dim3(128), 0, stream>>>(cow, cob, cog, cobe,
                                                    l2w, l2b, l2g, l2be, vw, vb,
                                                    statg, wsmg);
    prep2_kernel<<<dim3(NROWS / 256), dim3(256), 0, stream>>>(p3, az, el, p2d,
                                                              statg, Xg, curg);
    limb_kernel<true><<<dim3(NBLK), dim3(NTHR), 0, stream>>>(
        jf, p3, az, el, p2d, cow, cob, cog, cobe,
        l2w, l2b, l2g, l2be, vw, vb,
        h1b, hg, hbe, h2b, w3, h3b, wsb, Xg, curg, (float*)d_out);
  } else {
    limb_kernel<false><<<dim3(NBLK), dim3(NTHR), 0, stream>>>(
        jf, p3, az, el, p2d, cow, cob, cog, cobe,
        l2w, l2b, l2g, l2be, vw, vb,
        h1b, hg, hbe, h2b, w3, h3b, wsb, Xg, curg, (float*)d_out);
  }
}

// Round 17
// 292.072 us; speedup vs baseline: 2.2889x; 2.2889x over previous
//
#include <hip/hip_runtime.h>

// LimbOrientationPredictor fused kernel (MI355X / gfx950) — round 17
// EXACT RESTORE of round 15 (292us champion). r16's expand-MFMA regressed 2.3x via
// a 20x LDS bank-conflict explosion (X-tile stride pattern + per-tile global wsm
// reloads). Experiment ledger at this structure: r12 2-barrier (-3%), r13/r14
// reg-constants (spill, -56%), r16 expand-MFMA (-129%). r15 = measured optimum:
// VALU-issue bound at the compiler's hard 64-VGPR cap, VGPR 56, no spill,
// MfmaUtil 13.3%, VALUBusy 57%, bank conflicts at the structural floor.

#define NTHR   1024
#define NBLK   256
#define NTILES 14336   // 917504 / 64
#define NROWS  917504
#define C2D    6.66662222251852f   // 1/(0.15+1e-6)
#define RAD    0.017453292519943295f
#define WS_STAT_OFF 98304
#define WS_SCAL_OFF 131072

typedef __bf16 bf16x8 __attribute__((ext_vector_type(8)));
typedef __bf16 bf16x4 __attribute__((ext_vector_type(4)));
typedef float  f32x4  __attribute__((ext_vector_type(4)));

// PARENT-5 / CHILD-5 packed as 4-bit nibbles, l = 0..13
#define PARENT_PK 0x10106097863120ull
#define CHILD_PK  0x677671b9a85342ull

// ws layout: [0,65536) w1f bf16; [65536,98304) w2f bf16; [98304,+112) stats f32;
// [131072, +58720256) scal f32x4[NROWS*4].
__global__ __launch_bounds__(256) void prep_kernel(
    const float* __restrict__ w1, const float* __restrict__ w2,
    __bf16* __restrict__ wsb)
{
  const int u = blockIdx.x * 256 + threadIdx.x;   // 24*256 = 6144 tasks
  if (u < 4096) {
    const int lane = u & 63, t = u >> 6;
    const int f = t & 1, kk = (t >> 1) & 7, wn = t >> 4;
    const int col = wn * 32 + f * 16 + (lane & 15);
    const int kb  = kk * 32 + (lane >> 4) * 8;
    __bf16* dst = wsb + (size_t)u * 8;
    #pragma unroll
    for (int j = 0; j < 8; ++j) dst[j] = (__bf16)w1[col * 256 + kb + j];
  } else if (u < 6144) {
    const int v = u - 4096;
    const int lane = v & 63, t = v >> 6;
    const int f = t & 1, kk = (t >> 1) & 3, wn = t >> 3;
    const int col = wn * 32 + f * 16 + (lane & 15);
    const int kb  = kk * 32 + (lane >> 4) * 8;
    __bf16* dst = wsb + 32768 + (size_t)v * 8;
    #pragma unroll
    for (int j = 0; j < 8; ++j) dst[j] = (__bf16)w2[col * 128 + kb + j];
  }
}

// prep0: LN stats (one wave). statg[0..13]=l2 means+Q, [14..27]=co means+Q.
__global__ __launch_bounds__(64) void prep0_kernel(
    const float* __restrict__ cow, const float* __restrict__ cob,
    const float* __restrict__ l2w, const float* __restrict__ l2b,
    float* __restrict__ statg)
{
  const int o = threadIdx.x;
  const float w0 = l2w[o * 4 + 0], w1v = l2w[o * 4 + 1];
  const float w2v = l2w[o * 4 + 2] + C2D * l2w[o * 4 + 3];
  const float bo = l2b[o];
  float v[14] = { w0, w1v, w2v, bo, w0 * w0, w0 * w1v, w0 * w2v,
                  w1v * w1v, w1v * w2v, w2v * w2v, w0 * bo, w1v * bo, w2v * bo, bo * bo };
  float c0 = 0.f, c1 = 0.f, c2 = 0.f, cb = 0.f;
  if (o < 32) { c0 = cow[o * 3 + 0]; c1 = cow[o * 3 + 1]; c2 = cow[o * 3 + 2]; cb = cob[o]; }
  float u[14] = { c0, c1, c2, cb, c0 * c0, c0 * c1, c0 * c2,
                  c1 * c1, c1 * c2, c2 * c2, c0 * cb, c1 * cb, c2 * cb, cb * cb };
  #pragma unroll
  for (int k = 0; k < 14; ++k) {
    #pragma unroll
    for (int m = 1; m < 64; m <<= 1) { v[k] += __shfl_xor(v[k], m, 64); u[k] += __shfl_xor(u[k], m, 64); }
  }
  if (o == 0) {
    const float i64 = 1.f / 64.f, i32 = 1.f / 32.f;
    const float lmx = v[0] * i64, lmy = v[1] * i64, lmz = v[2] * i64, lmb = v[3] * i64;
    statg[0] = lmx; statg[1] = lmy; statg[2] = lmz; statg[3] = lmb;
    statg[4] = v[4] * i64 - lmx * lmx;        statg[5] = 2.f * (v[5] * i64 - lmx * lmy);
    statg[6] = 2.f * (v[6] * i64 - lmx * lmz); statg[7] = v[7] * i64 - lmy * lmy;
    statg[8] = 2.f * (v[8] * i64 - lmy * lmz); statg[9] = v[9] * i64 - lmz * lmz;
    statg[10] = 2.f * (v[10] * i64 - lmx * lmb); statg[11] = 2.f * (v[11] * i64 - lmy * lmb);
    statg[12] = 2.f * (v[12] * i64 - lmz * lmb); statg[13] = v[13] * i64 - lmb * lmb;
    const float cmx = u[0] * i32, cmy = u[1] * i32, cmz = u[2] * i32, cmb = u[3] * i32;
    statg[14] = cmx; statg[15] = cmy; statg[16] = cmz; statg[17] = cmb;
    statg[18] = u[4] * i32 - cmx * cmx;        statg[19] = 2.f * (u[5] * i32 - cmx * cmy);
    statg[20] = 2.f * (u[6] * i32 - cmx * cmz); statg[21] = u[7] * i32 - cmy * cmy;
    statg[22] = 2.f * (u[8] * i32 - cmy * cmz); statg[23] = u[9] * i32 - cmz * cmz;
    statg[24] = 2.f * (u[10] * i32 - cmx * cmb); statg[25] = 2.f * (u[11] * i32 - cmy * cmb);
    statg[26] = 2.f * (u[12] * i32 - cmz * cmb); statg[27] = u[13] * i32 - cmb * cmb;
  }
}

// prep2: scal[16]/row at full lane utilization (one row per thread).
__global__ __launch_bounds__(256) void prep2_kernel(
    const float* __restrict__ p3g, const float* __restrict__ az,
    const float* __restrict__ el,  const float* __restrict__ p2d,
    const float* __restrict__ statg, f32x4* __restrict__ scalg)
{
  const int r = blockIdx.x * 256 + threadIdx.x;   // 3584*256 = 917504 exact
  const unsigned rg = (unsigned)r;
  const unsigned b = rg / 14u;
  const int l = (int)(rg - b * 14u);
  const int p = 5 + (int)((PARENT_PK >> (4 * l)) & 15ull);
  const int c = 5 + (int)((CHILD_PK  >> (4 * l)) & 15ull);
  const float* p3 = p3g + (size_t)b * 51;
  const float dx = p3[c * 3 + 0] - p3[p * 3 + 0];
  const float dy = p3[c * 3 + 1] - p3[p * 3 + 1];
  const float dz = p3[c * 3 + 2] - p3[p * 3 + 2];
  const float* q2 = p2d + (size_t)b * 34;
  const float vx = q2[c * 2 + 0] - q2[p * 2 + 0];
  const float vy = q2[c * 2 + 1] - q2[p * 2 + 1];
  const float sazv = az[b], selv = el[b];

  const float ci = 1.f / fmaxf(sqrtf(dx * dx + dy * dy + dz * dz), 1e-6f);
  const float cx = dx * ci, cy = dy * ci, cz = dz * ci;
  const float L  = sqrtf(vx * vx + vy * vy);
  const float il = 1.f / (L + 1e-6f);
  const float f0 = vx * il, f1 = vy * il;
  const float azr = sazv * RAD, elr = selv * RAD;
  const float sa = __sinf(azr), ca = __cosf(azr);
  const float se = __sinf(elr), ce = __cosf(elr);
  const float vl = statg[4] * f0 * f0 + statg[7] * f1 * f1 + statg[9] * L * L +
                   statg[5] * f0 * f1 + statg[6] * f0 * L + statg[8] * f1 * L +
                   statg[10] * f0 + statg[11] * f1 + statg[12] * L + statg[13];
  const float vc = statg[18] * cx * cx + statg[21] * cy * cy + statg[23] * cz * cz +
                   statg[19] * cx * cy + statg[20] * cx * cz + statg[22] * cy * cz +
                   statg[24] * cx + statg[25] * cy + statg[26] * cz + statg[27];
  f32x4 s0; s0[0] = cx; s0[1] = cy; s0[2] = cz; s0[3] = f0;
  f32x4 s1; s1[0] = f1; s1[1] = L; s1[2] = rsqrtf(vl + 1e-5f); s1[3] = rsqrtf(vc + 1e-5f);
  f32x4 s2; s2[0] = sa * ce; s2[1] = se; s2[2] = ca * ce; s2[3] = sa;
  f32x4 s3; s3[0] = ca; s3[1] = ce; s3[2] = 0.f; s3[3] = 0.f;
  scalg[(size_t)r * 4 + 0] = s0; scalg[(size_t)r * 4 + 1] = s1;
  scalg[(size_t)r * 4 + 2] = s2; scalg[(size_t)r * 4 + 3] = s3;
}

struct Smem {
  __bf16 w1f[32768];     // 65536B
  __bf16 w2f[16384];     // 32768B
  __bf16 lf[64][264];    // 33792B feature tile
  __bf16 h [64][132];    // 16896B post-LN h tile
  f32x4  scal4[256];     // 4096B
  float  w3c[384];       // 1536B h3_w as [o*128+m]
  float  h1b[128], hg[128], hbe[128], h2b[128];  // 2048B
  float  partG1[512];    // 2048B (ss,qq) at [nrow*8 + mp*2]
  float  partG2[768];    // 3072B p at [nrow*12 + c*4 + mp]
};                        // total 161792B -> 1 block/CU, 16 waves

// Force wave-uniform float to SGPR (bit-cast: readfirstlane is int-typed).
__device__ __forceinline__ float RFL(float x) {
  return __uint_as_float((unsigned)__builtin_amdgcn_readfirstlane((int)__float_as_uint(x)));
}

template<bool PRECOMP>
__global__ __launch_bounds__(NTHR, 4) void limb_kernel(
    const float* __restrict__ jf,  const float* __restrict__ p3g,
    const float* __restrict__ az,  const float* __restrict__ el,
    const float* __restrict__ p2d,
    const float* __restrict__ cow, const float* __restrict__ cob,
    const float* __restrict__ cog, const float* __restrict__ cobe,
    const float* __restrict__ l2w, const float* __restrict__ l2b,
    const float* __restrict__ l2g, const float* __restrict__ l2be,
    const float* __restrict__ vw,  const float* __restrict__ vb,
    const float* __restrict__ h1bg, const float* __restrict__ hgg,
    const float* __restrict__ hbeg, const float* __restrict__ h2bg,
    const float* __restrict__ w3,  const float* __restrict__ h3bg,
    const __bf16* __restrict__ wsb, const f32x4* __restrict__ scalg,
    float* __restrict__ out)
{
  __shared__ Smem sm;
  const int tid  = threadIdx.x;
  const int wave = tid >> 6;
  const int lane = tid & 63;
  const int lrow = lane & 15, lk8 = lane >> 4;
  const int mp = wave >> 2, nt = wave & 3;   // M-pair (weight cols) x N-tile (rows)
  const int nrow = nt * 16 + lrow;           // this lane's data row in MFMA phases
  const int cb0 = mp * 32 + lk8 * 4;         // out-col base (f=0); f=1 at +16
  const int cb1 = cb0 + 16;
  const int myrow0 = wave * 4;               // wave-owned rows

  // ---- one-time staging ----
  {
    const uint4* s1 = (const uint4*)wsb;
    uint4* d1 = (uint4*)sm.w1f;
    for (int i = tid; i < 4096; i += NTHR) d1[i] = s1[i];
    const uint4* s2 = (const uint4*)(wsb + 32768);
    uint4* d2 = (uint4*)sm.w2f;
    for (int i = tid; i < 2048; i += NTHR) d2[i] = s2[i];
  }
  if (tid < 384) sm.w3c[tid] = w3[tid];
  if (tid < 128) {
    sm.h1b[tid] = h1bg[tid]; sm.hg[tid] = hgg[tid];
    sm.hbe[tid] = hbeg[tid]; sm.h2b[tid] = h2bg[tid];
  }
  const float h3b0 = h3bg[0], h3b1 = h3bg[1], h3b2 = h3bg[2];

  // ---- closed-form LN stats (lwc/u params need means; Q terms: fallback only) ----
  float lQxx, lQxy2, lQxz2, lQyy, lQyz2, lQzz, lrx2, lry2, lrz2, ls0;
  float lmx, lmy, lmz, lmb;
  {
    float s1x = 0, s1y = 0, s1z = 0, sb = 0;
    float sxx = 0, sxy = 0, sxz = 0, syy = 0, syz = 0, szz = 0;
    float sbx = 0, sby = 0, sbz = 0, sbb = 0;
    for (int o = 0; o < 64; ++o) {
      const float w0 = l2w[o * 4 + 0], w1v = l2w[o * 4 + 1];
      const float w2v = l2w[o * 4 + 2] + C2D * l2w[o * 4 + 3];
      const float bo = l2b[o];
      s1x += w0; s1y += w1v; s1z += w2v; sb += bo;
      sxx += w0 * w0; sxy += w0 * w1v; sxz += w0 * w2v;
      syy += w1v * w1v; syz += w1v * w2v; szz += w2v * w2v;
      sbx += w0 * bo; sby += w1v * bo; sbz += w2v * bo; sbb += bo * bo;
    }
    const float i = 1.f / 64.f;
    lmx = RFL(s1x * i); lmy = RFL(s1y * i); lmz = RFL(s1z * i); lmb = RFL(sb * i);
    lQxx = RFL(sxx * i - lmx * lmx); lQxy2 = RFL(2.f * (sxy * i - lmx * lmy));
    lQxz2 = RFL(2.f * (sxz * i - lmx * lmz)); lQyy = RFL(syy * i - lmy * lmy);
    lQyz2 = RFL(2.f * (syz * i - lmy * lmz)); lQzz = RFL(szz * i - lmz * lmz);
    lrx2 = RFL(2.f * (sbx * i - lmx * lmb)); lry2 = RFL(2.f * (sby * i - lmy * lmb));
    lrz2 = RFL(2.f * (sbz * i - lmz * lmb)); ls0 = RFL(sbb * i - lmb * lmb);
  }
  float cQxx, cQxy2, cQxz2, cQyy, cQyz2, cQzz, crx2, cry2, crz2, cs0;
  float cmx, cmy, cmz, cmb;
  {
    float s1x = 0, s1y = 0, s1z = 0, sb = 0;
    float sxx = 0, sxy = 0, sxz = 0, syy = 0, syz = 0, szz = 0;
    float sbx = 0, sby = 0, sbz = 0, sbb = 0;
    for (int o = 0; o < 32; ++o) {
      const float w0 = cow[o * 3 + 0], w1v = cow[o * 3 + 1], w2v = cow[o * 3 + 2];
      const float bo = cob[o];
      s1x += w0; s1y += w1v; s1z += w2v; sb += bo;
      sxx += w0 * w0; sxy += w0 * w1v; sxz += w0 * w2v;
      syy += w1v * w1v; syz += w1v * w2v; szz += w2v * w2v;
      sbx += w0 * bo; sby += w1v * bo; sbz += w2v * bo; sbb += bo * bo;
    }
    const float i = 1.f / 32.f;
    cmx = RFL(s1x * i); cmy = RFL(s1y * i); cmz = RFL(s1z * i); cmb = RFL(sb * i);
    cQxx = RFL(sxx * i - cmx * cmx); cQxy2 = RFL(2.f * (sxy * i - cmx * cmy));
    cQxz2 = RFL(2.f * (sxz * i - cmx * cmz)); cQyy = RFL(syy * i - cmy * cmy);
    cQyz2 = RFL(2.f * (syz * i - cmy * cmz)); cQzz = RFL(szz * i - cmz * cmz);
    crx2 = RFL(2.f * (sbx * i - cmx * cmb)); cry2 = RFL(2.f * (sby * i - cmy * cmb));
    crz2 = RFL(2.f * (sbz * i - cmz * cmb)); cs0 = RFL(sbb * i - cmb * cmb);
  }

  // ---- per-lane small-net params ----
  const float lwc0 = l2w[lane * 4 + 0] - lmx;
  const float lwc1 = l2w[lane * 4 + 1] - lmy;
  const float lwc2 = (l2w[lane * 4 + 2] + C2D * l2w[lane * 4 + 3]) - lmz;
  const float lbc  = l2b[lane] - lmb;
  const float lgv  = l2g[lane], lbev = l2be[lane];
  float u0, u1, u2, u3, u4, u5, u6;
  if (lane < 32) {
    u0 = cow[lane * 3 + 0] - cmx; u1 = cow[lane * 3 + 1] - cmy;
    u2 = cow[lane * 3 + 2] - cmz; u3 = cob[lane] - cmb;
    u4 = cog[lane]; u5 = cobe[lane]; u6 = 0.f;
  } else {
    const int o = lane - 32;
    u0 = vw[o * 7 + 0]; u1 = vw[o * 7 + 1] + vw[o * 7 + 5];
    u2 = vw[o * 7 + 2]; u3 = vw[o * 7 + 3];
    u4 = vw[o * 7 + 4]; u5 = vw[o * 7 + 6]; u6 = vb[o];
  }

  // ---- helpers ----
  auto jf_src = [&](int rg0x, int round) -> const float* {
    const int task = wave * 8 + round * 4 + lk8;
    const int row = task >> 1, half = task & 1;
    const unsigned rg = (unsigned)(rg0x + row);
    const unsigned b = rg / 14u;
    const int l = (int)(rg - b * 14u);
    const int j = half ? 5 + (int)((CHILD_PK >> (4 * l)) & 15ull)
                       : 5 + (int)((PARENT_PK >> (4 * l)) & 15ull);
    return jf + ((size_t)b * 17 + (size_t)j) * 64 + lrow * 4;
  };
  auto jf_store = [&](int round, float4 v) {
    const int task = wave * 8 + round * 4 + lk8;
    const int row = task >> 1, half = task & 1;
    bf16x4 o; o[0] = (__bf16)v.x; o[1] = (__bf16)v.y; o[2] = (__bf16)v.z; o[3] = (__bf16)v.w;
    *(bf16x4*)&sm.lf[row][(half ? 160 : 96) + lrow * 4] = o;
  };
  struct G12 { float p3p0, p3p1, p3p2, p3c0, p3c1, p3c2, q2p0, q2p1, q2c0, q2c1, sazv, selv; };
  auto gather12_row = [&](int rgl) -> G12 {
    G12 g;
    const unsigned rg = (unsigned)rgl;
    const unsigned b = rg / 14u;
    const int l = (int)(rg - b * 14u);
    const int p = 5 + (int)((PARENT_PK >> (4 * l)) & 15ull);
    const int c = 5 + (int)((CHILD_PK  >> (4 * l)) & 15ull);
    const float* p3 = p3g + (size_t)b * 51;
    g.p3p0 = p3[p * 3 + 0]; g.p3p1 = p3[p * 3 + 1]; g.p3p2 = p3[p * 3 + 2];
    g.p3c0 = p3[c * 3 + 0]; g.p3c1 = p3[c * 3 + 1]; g.p3c2 = p3[c * 3 + 2];
    const float* q2 = p2d + (size_t)b * 34;
    g.q2p0 = q2[p * 2 + 0]; g.q2p1 = q2[p * 2 + 1];
    g.q2c0 = q2[c * 2 + 0]; g.q2c1 = q2[c * 2 + 1];
    g.sazv = az[b]; g.selv = el[b];
    return g;
  };
  auto scal_write = [&](int row, const G12& g) {
    const float dx = g.p3c0 - g.p3p0, dy = g.p3c1 - g.p3p1, dz = g.p3c2 - g.p3p2;
    const float ci = 1.f / fmaxf(sqrtf(dx * dx + dy * dy + dz * dz), 1e-6f);
    const float cx = dx * ci, cy = dy * ci, cz = dz * ci;
    const float vx = g.q2c0 - g.q2p0, vy = g.q2c1 - g.q2p1;
    const float L  = sqrtf(vx * vx + vy * vy);
    const float il = 1.f / (L + 1e-6f);
    const float f0 = vx * il, f1 = vy * il;
    const float azr = g.sazv * RAD, elr = g.selv * RAD;
    const float sa = __sinf(azr), ca = __cosf(azr);
    const float se = __sinf(elr), ce = __cosf(elr);
    const float vl = lQxx * f0 * f0 + lQyy * f1 * f1 + lQzz * L * L +
                     lQxy2 * f0 * f1 + lQxz2 * f0 * L + lQyz2 * f1 * L +
                     lrx2 * f0 + lry2 * f1 + lrz2 * L + ls0;
    const float vc = cQxx * cx * cx + cQyy * cy * cy + cQzz * cz * cz +
                     cQxy2 * cx * cy + cQxz2 * cx * cz + cQyz2 * cy * cz +
                     crx2 * cx + cry2 * cy + crz2 * cz + cs0;
    f32x4 s0; s0[0] = cx; s0[1] = cy; s0[2] = cz; s0[3] = f0;
    f32x4 s1; s1[0] = f1; s1[1] = L; s1[2] = rsqrtf(vl + 1e-5f); s1[3] = rsqrtf(vc + 1e-5f);
    f32x4 s2; s2[0] = sa * ce; s2[1] = se; s2[2] = ca * ce; s2[3] = sa;
    f32x4 s3; s3[0] = ca; s3[1] = ce; s3[2] = 0.f; s3[3] = 0.f;
    sm.scal4[row * 4 + 0] = s0; sm.scal4[row * 4 + 1] = s1;
    sm.scal4[row * 4 + 2] = s2; sm.scal4[row * 4 + 3] = s3;
  };
  auto expandB = [&]() {   // l2/co/vf for this wave's 4 rows (same-wave scal visibility)
    #pragma unroll
    for (int rr = 0; rr < 4; ++rr) {
      const int row = myrow0 + rr;
      const f32x4 s0 = sm.scal4[row * 4 + 0];
      const f32x4 s1 = sm.scal4[row * 4 + 1];
      const f32x4 s2 = sm.scal4[row * 4 + 2];
      const f32x4 s3 = sm.scal4[row * 4 + 3];
      {
        const float a = lwc0 * s0[3] + lwc1 * s1[0] + lwc2 * s1[1] + lbc;
        sm.lf[row][lane] = (__bf16)fmaxf(a * s1[2] * lgv + lbev, 0.f);
      }
      if (lane < 32) {
        const float a = u0 * s0[0] + u1 * s0[1] + u2 * s0[2] + u3;
        sm.lf[row][64 + lane] = (__bf16)fmaxf(a * s1[3] * u4 + u5, 0.f);
      } else {
        const float a = u0 * s2[0] + u1 * s2[1] + u2 * s2[2] + u3 * s2[3] +
                        u4 * s3[0] + u5 * s3[1] + u6;
        sm.lf[row][224 + (lane - 32)] = (__bf16)fmaxf(a, 0.f);
      }
    }
  };

  // ---- prologue: stage tile0 fully ----
  {
    const int rg0 = blockIdx.x * 64;
    jf_store(0, *(const float4*)jf_src(rg0, 0));
    jf_store(1, *(const float4*)jf_src(rg0, 1));
    if (PRECOMP) {
      if (lane < 16)   // one f32x4 per lane: rows myrow0..+3 x vec 0..3
        sm.scal4[(myrow0 + (lane >> 2)) * 4 + (lane & 3)] =
            scalg[(size_t)(rg0 + myrow0 + (lane >> 2)) * 4 + (lane & 3)];
    } else if (lane < 4) {
      scal_write(myrow0 + lane, gather12_row(rg0 + myrow0 + lane));
    }
    expandB();
  }
  __syncthreads();

  float curx = 0.f, cury = 0.f, curz = 0.f;
  int prevT = -1;

  for (int tile = blockIdx.x; tile < NTILES; tile += NBLK) {
    const int ntile = tile + NBLK;
    const bool pv = ntile < NTILES;

    // ===== G1 phase: prefetch issue(t+1) + finalize(t-1) + G1 MFMA =====
    float4 jva = {0.f, 0.f, 0.f, 0.f}, jvb = jva;
    f32x4 sn = {0.f, 0.f, 0.f, 0.f};
    G12 g = {};
    if (pv) {
      jva = *(const float4*)jf_src(ntile * 64, 0);
      jvb = *(const float4*)jf_src(ntile * 64, 1);
      if (PRECOMP) {
        if (lane < 16)
          sn = scalg[(size_t)(ntile * 64 + myrow0 + (lane >> 2)) * 4 + (lane & 3)];
      } else if (lane < 4) {
        g = gather12_row(ntile * 64 + myrow0 + lane);
      }
    }
    if (prevT >= 0 && lane < 4) {   // finalize(prevT)
      const int r = myrow0 + lane;
      const f32x4 q0 = *(const f32x4*)&sm.partG2[r * 12];
      const f32x4 q1 = *(const f32x4*)&sm.partG2[r * 12 + 4];
      const f32x4 q2 = *(const f32x4*)&sm.partG2[r * 12 + 8];
      const float ox = curx + q0[0] + q0[1] + q0[2] + q0[3] + h3b0;
      const float oy = cury + q1[0] + q1[1] + q1[2] + q1[3] + h3b1;
      const float oz = curz + q2[0] + q2[1] + q2[2] + q2[3] + h3b2;
      const float nn = sqrtf(ox * ox + oy * oy + oz * oz);
      const float iv = 1.f / fmaxf(nn, 1e-6f);
      const size_t o0 = (size_t)(prevT * 64 + r) * 3;
      out[o0 + 0] = ox * iv; out[o0 + 1] = oy * iv; out[o0 + 2] = oz * iv;
    }
    f32x4 a0 = {0.f, 0.f, 0.f, 0.f}, a1 = a0;
    #pragma unroll
    for (int kk = 0; kk < 8; ++kk) {
      const bf16x8 fb  = *(const bf16x8*)&sm.lf[nrow][kk * 32 + lk8 * 8];
      const bf16x8 fa0 = *(const bf16x8*)&sm.w1f[(((mp * 8 + kk) * 2 + 0) * 64 + lane) * 8];
      const bf16x8 fa1 = *(const bf16x8*)&sm.w1f[(((mp * 8 + kk) * 2 + 1) * 64 + lane) * 8];
      a0 = __builtin_amdgcn_mfma_f32_16x16x32_bf16(fa0, fb, a0, 0, 0, 0);
      a1 = __builtin_amdgcn_mfma_f32_16x16x32_bf16(fa1, fb, a1, 0, 0, 0);
    }
    const f32x4 hb0 = *(const f32x4*)&sm.h1b[cb0];
    const f32x4 hb1 = *(const f32x4*)&sm.h1b[cb1];
    float v0[4], v1[4], ss = 0.f, qq = 0.f;
    #pragma unroll
    for (int j = 0; j < 4; ++j) {
      v0[j] = a0[j] + hb0[j]; v1[j] = a1[j] + hb1[j];
      ss += v0[j] + v1[j];
      qq = fmaf(v0[j], v0[j], qq); qq = fmaf(v1[j], v1[j], qq);
    }
    ss += __shfl_xor(ss, 16, 64); ss += __shfl_xor(ss, 32, 64);
    qq += __shfl_xor(qq, 16, 64); qq += __shfl_xor(qq, 32, 64);
    if (lk8 == 0) *(float2*)&sm.partG1[nrow * 8 + mp * 2] = make_float2(ss, qq);
    __syncthreads();   // B1

    // ===== LN phase: apply + write h =====
    {
      const f32x4 pa = *(const f32x4*)&sm.partG1[nrow * 8];
      const f32x4 pb = *(const f32x4*)&sm.partG1[nrow * 8 + 4];
      const float mean = (pa[0] + pa[2] + pb[0] + pb[2]) * (1.f / 128.f);
      const float var  = (pa[1] + pa[3] + pb[1] + pb[3]) * (1.f / 128.f) - mean * mean;
      const float rs = rsqrtf(var + 1e-5f);
      const f32x4 g0 = *(const f32x4*)&sm.hg[cb0],  g1 = *(const f32x4*)&sm.hg[cb1];
      const f32x4 e0 = *(const f32x4*)&sm.hbe[cb0], e1 = *(const f32x4*)&sm.hbe[cb1];
      bf16x4 y0, y1;
      #pragma unroll
      for (int j = 0; j < 4; ++j) {
        float t0 = (v0[j] - mean) * rs * g0[j] + e0[j]; t0 = (t0 > 0.f) ? t0 : 0.2f * t0;
        float t1 = (v1[j] - mean) * rs * g1[j] + e1[j]; t1 = (t1 > 0.f) ? t1 : 0.2f * t1;
        y0[j] = (__bf16)t0; y1[j] = (__bf16)t1;
      }
      *(bf16x4*)&sm.h[nrow][cb0] = y0;
      *(bf16x4*)&sm.h[nrow][cb1] = y1;
    }
    __syncthreads();   // B2

    // ===== G2 phase: G2 MFMA + epilogue, overlapped with stage/scal/expand(t+1) =====
    f32x4 d0 = {0.f, 0.f, 0.f, 0.f}, d1 = d0;
    #pragma unroll
    for (int kk = 0; kk < 4; ++kk) {
      const bf16x8 fbh = *(const bf16x8*)&sm.h[nrow][kk * 32 + lk8 * 8];
      const bf16x8 fa0 = *(const bf16x8*)&sm.w2f[(((mp * 4 + kk) * 2 + 0) * 64 + lane) * 8];
      const bf16x8 fa1 = *(const bf16x8*)&sm.w2f[(((mp * 4 + kk) * 2 + 1) * 64 + lane) * 8];
      d0 = __builtin_amdgcn_mfma_f32_16x16x32_bf16(fa0, fbh, d0, 0, 0, 0);
      d1 = __builtin_amdgcn_mfma_f32_16x16x32_bf16(fa1, fbh, d1, 0, 0, 0);
    }
    if (pv) { jf_store(0, jva); jf_store(1, jvb); }   // lf free since B1
    if (lane < 4) {
      const f32x4 cu = sm.scal4[(myrow0 + lane) * 4];  // save cur(t) before overwrite
      curx = cu[0]; cury = cu[1]; curz = cu[2];
    }
    if (pv) {   // scal(t+1) write AFTER the cur-save read (same-wave LDS ordering)
      if (PRECOMP) {
        if (lane < 16)
          sm.scal4[(myrow0 + (lane >> 2)) * 4 + (lane & 3)] = sn;
      } else if (lane < 4) {
        scal_write(myrow0 + lane, g);
      }
    }
    {
      const f32x4 b20 = *(const f32x4*)&sm.h2b[cb0], b21 = *(const f32x4*)&sm.h2b[cb1];
      const f32x4 wx0 = *(const f32x4*)&sm.w3c[cb0],        wx1 = *(const f32x4*)&sm.w3c[cb1];
      const f32x4 wy0 = *(const f32x4*)&sm.w3c[128 + cb0],  wy1 = *(const f32x4*)&sm.w3c[128 + cb1];
      const f32x4 wz0 = *(const f32x4*)&sm.w3c[256 + cb0],  wz1 = *(const f32x4*)&sm.w3c[256 + cb1];
      float p0 = 0.f, p1 = 0.f, p2 = 0.f;
      #pragma unroll
      for (int j = 0; j < 4; ++j) {
        float x0 = d0[j] + b20[j]; x0 = (x0 > 0.f) ? x0 : 0.2f * x0;
        float x1 = d1[j] + b21[j]; x1 = (x1 > 0.f) ? x1 : 0.2f * x1;
        p0 = fmaf(x0, wx0[j], fmaf(x1, wx1[j], p0));
        p1 = fmaf(x0, wy0[j], fmaf(x1, wy1[j], p1));
        p2 = fmaf(x0, wz0[j], fmaf(x1, wz1[j], p2));
      }
      p0 += __shfl_xor(p0, 16, 64); p0 += __shfl_xor(p0, 32, 64);
      p1 += __shfl_xor(p1, 16, 64); p1 += __shfl_xor(p1, 32, 64);
      p2 += __shfl_xor(p2, 16, 64); p2 += __shfl_xor(p2, 32, 64);
      if (lk8 == 0) {
        sm.partG2[nrow * 12 + 0 + mp] = p0;
        sm.partG2[nrow * 12 + 4 + mp] = p1;
        sm.partG2[nrow * 12 + 8 + mp] = p2;
      }
    }
    if (pv) expandB();
    __syncthreads();     // B3
    prevT = tile;
  }

  // ---- epilogue: finalize the last tile ----
  if (lane < 4) {
    const int r = myrow0 + lane;
    const f32x4 q0 = *(const f32x4*)&sm.partG2[r * 12];
    const f32x4 q1 = *(const f32x4*)&sm.partG2[r * 12 + 4];
    const f32x4 q2 = *(const f32x4*)&sm.partG2[r * 12 + 8];
    const float ox = curx + q0[0] + q0[1] + q0[2] + q0[3] + h3b0;
    const float oy = cury + q1[0] + q1[1] + q1[2] + q1[3] + h3b1;
    const float oz = curz + q2[0] + q2[1] + q2[2] + q2[3] + h3b2;
    const float nn = sqrtf(ox * ox + oy * oy + oz * oz);
    const float iv = 1.f / fmaxf(nn, 1e-6f);
    const size_t o0 = (size_t)(prevT * 64 + r) * 3;
    out[o0 + 0] = ox * iv; out[o0 + 1] = oy * iv; out[o0 + 2] = oz * iv;
  }
}

extern "C" void kernel_launch(void* const* d_in, const int* in_sizes, int n_in,
                              void* d_out, int out_size, void* d_ws, size_t ws_size,
                              hipStream_t stream) {
  (void)in_sizes; (void)n_in; (void)out_size;
  const float* jf   = (const float*)d_in[0];
  // d_in[1] = pose_2d (unused by the reference)
  const float* p3   = (const float*)d_in[2];
  const float* az   = (const float*)d_in[3];
  const float* el   = (const float*)d_in[4];
  const float* p2d  = (const float*)d_in[5];
  const float* cow  = (const float*)d_in[6];
  const float* cob  = (const float*)d_in[7];
  const float* cog  = (const float*)d_in[8];
  const float* cobe = (const float*)d_in[9];
  const float* l2w  = (const float*)d_in[10];
  const float* l2b  = (const float*)d_in[11];
  const float* l2g  = (const float*)d_in[12];
  const float* l2be = (const float*)d_in[13];
  const float* vw   = (const float*)d_in[14];
  const float* vb   = (const float*)d_in[15];
  const float* w1   = (const float*)d_in[16];
  const float* h1b  = (const float*)d_in[17];
  const float* hg   = (const float*)d_in[18];
  const float* hbe  = (const float*)d_in[19];
  const float* w2   = (const float*)d_in[20];
  const float* h2b  = (const float*)d_in[21];
  const float* w3   = (const float*)d_in[22];
  const float* h3b  = (const float*)d_in[23];

  __bf16* wsb   = (__bf16*)d_ws;
  float*  statg = (float*)((char*)d_ws + WS_STAT_OFF);
  f32x4*  scalg = (f32x4*)((char*)d_ws + WS_SCAL_OFF);

  const size_t ws_need = (size_t)WS_SCAL_OFF + (size_t)NROWS * 64;
  const bool pre = ws_size >= ws_need;

  prep_kernel<<<dim3(24), dim3(256), 0, stream>>>(w1, w2, wsb);
  if (pre) {
    prep0_kernel<<<dim3(1), dim3(64), 0, stream>>>(cow, cob, l2w, l2b, statg);
    prep2_kernel<<<dim3(NROWS / 256), dim3(256), 0, stream>>>(p3, az, el, p2d, statg, scalg);
    limb_kernel<true><<<dim3(NBLK), dim3(NTHR), 0, stream>>>(
        jf, p3, az, el, p2d, cow, cob, cog, cobe,
        l2w, l2b, l2g, l2be, vw, vb,
        h1b, hg, hbe, h2b, w3, h3b, wsb, scalg, (float*)d_out);
  } else {
    limb_kernel<false><<<dim3(NBLK), dim3(NTHR), 0, stream>>>(
        jf, p3, az, el, p2d, cow, cob, cog, cobe,
        l2w, l2b, l2g, l2be, vw, vb,
        h1b, hg, hbe, h2b, w3, h3b, wsb, scalg, (float*)d_out);
  }
}